// Round 6
// baseline (32809.238 us; speedup 1.0000x reference)
//
#include <hip/hip_runtime.h>
#include <stdint.h>
#include <math.h>

#define TT 256
#define VOCAB 32000
#define LN_EPS 1e-5

typedef __attribute__((ext_vector_type(8))) short bf16x8;
typedef __attribute__((ext_vector_type(4))) float f32x4;

__device__ __forceinline__ float bf2f(short s) {
  return __uint_as_float(((uint32_t)(uint16_t)s) << 16);
}
__device__ __forceinline__ short f2bf(float f) {
  uint32_t u = __float_as_uint(f);
  u += 0x7fffu + ((u >> 16) & 1u);
  return (short)(u >> 16);
}
__device__ __forceinline__ f32x4 mfma16(bf16x8 a, bf16x8 b, f32x4 c) {
  return __builtin_amdgcn_mfma_f32_16x16x32_bf16(a, b, c, 0, 0, 0);
}

// ---------------- one pipeline phase as ONE LAUNCH (no grid barrier) ----------------
// launch p, grid 448: blocks 0..127 layer0(t=p, 8 cols each), 128..383 layer1(t=p-1,
// 4 cols each), 384..447 head-pre(t=p-2, 16 cols each).
// RECURRENT PATH IS FP64: the GRU+LN chain amplifies per-step rounding by ~1e5-1e6
// over 256 steps (round-5 evidence: f32+__expf -> 0.325; bf16 -> decorrelation).
struct PH {
  const int* input; const float* embd;
  const float *Wih0, *Whh0, *bih0, *bhh0, *ln0w, *ln0b;
  const float *Wih1, *Whh1, *bih1, *bhh1, *ln1w, *ln1b;
  const float *W1, *b1;
  double *h0ring, *h1ring;  // [2][16][1024] f64, raw (pre-LN) hidden states
  short *araw;              // [4096][1024] bf16, post-LeakyReLU head activations
  int p;
};

__launch_bounds__(256, 1)
__global__ void k_phase(PH A) {
  const int tid = threadIdx.x;
  const int row = tid >> 4;  // batch 0..15
  const int ks = tid & 15;   // k-slice 0..15 (64 elems each)
  const int kb = ks * 64;
  const int bid = blockIdx.x;

  if (bid < 128) {
    // ---------------- layer0, t = p ----------------
    const int t = A.p;
    if (t >= TT) return;
    const int col0 = bid * 8;  // 0..1016
    double an[64];
    double m = 0.0, rs = 0.0;
    if (t > 0) {
      const double* hp = A.h0ring + ((t - 1) & 1) * 16384 + row * 1024 + kb;
      double s = 0.0, q = 0.0;
#pragma unroll
      for (int j = 0; j < 64; ++j) { double v = hp[j]; an[j] = v; s += v; q += v * v; }
#pragma unroll
      for (int mk = 1; mk <= 8; mk <<= 1) { s += __shfl_xor(s, mk); q += __shfl_xor(q, mk); }
      m = s * (1.0 / 1024.0);
      rs = 1.0 / sqrt(q * (1.0 / 1024.0) - m * m + LN_EPS);
#pragma unroll
      for (int j = 0; j < 64; ++j)
        an[j] = (an[j] - m) * rs * (double)A.ln0w[kb + j] + (double)A.ln0b[kb + j];
    } else {
#pragma unroll
      for (int j = 0; j < 64; ++j) an[j] = 0.0;
    }
    const int tok = A.input[row * TT + t];
    float xe[32];
    const float* ep = A.embd + (size_t)tok * 512 + ks * 32;
#pragma unroll
    for (int j = 0; j < 32; ++j) xe[j] = ep[j];

    for (int cc = 0; cc < 8; ++cc) {
      const int c = col0 + cc;  // <= 1023
      double gI[3], gH[3];
#pragma unroll
      for (int g = 0; g < 3; ++g) {
        const float* wI = A.Wih0 + (size_t)(g * 1024 + c) * 512 + ks * 32;
        const float* wH = A.Whh0 + (size_t)(g * 1024 + c) * 1024 + kb;
        double aI = 0.0, aH = 0.0;
#pragma unroll
        for (int j = 0; j < 32; ++j) aI = fma((double)xe[j], (double)wI[j], aI);
#pragma unroll
        for (int j = 0; j < 64; ++j) aH = fma(an[j], (double)wH[j], aH);
#pragma unroll
        for (int mk = 1; mk <= 8; mk <<= 1) { aI += __shfl_xor(aI, mk); aH += __shfl_xor(aH, mk); }
        gI[g] = aI; gH[g] = aH;
      }
      const double ir = gI[0] + (double)A.bih0[c],         hr = gH[0] + (double)A.bhh0[c];
      const double iz = gI[1] + (double)A.bih0[c + 1024],  hz = gH[1] + (double)A.bhh0[c + 1024];
      const double in_ = gI[2] + (double)A.bih0[c + 2048], hn = gH[2] + (double)A.bhh0[c + 2048];
      const double r_ = 1.0 / (1.0 + exp(-(ir + hr)));
      const double z = 1.0 / (1.0 + exp(-(iz + hz)));
      const double n = tanh(in_ + r_ * hn);
      double hprev = 0.0;
      if (t > 0) {
        const double praw = A.h0ring[((t - 1) & 1) * 16384 + row * 1024 + c];
        hprev = (praw - m) * rs * (double)A.ln0w[c] + (double)A.ln0b[c];
      }
      const double hnew = (1.0 - z) * n + z * hprev;
      if (ks == 0) A.h0ring[(t & 1) * 16384 + row * 1024 + c] = hnew;
    }
  } else if (bid < 384) {
    // ---------------- layer1, t = p-1 (two-pass to cap registers) ----------------
    const int t = A.p - 1;
    if (t < 0 || t >= TT) return;
    const int col0 = (bid - 128) * 4;  // 0..1020
    double gI[4][3];
    // ---- pass A: a0 = LN0(h0[t]) and the Wih1 dots ----
    {
      double a0[64];
      const double* hp = A.h0ring + (t & 1) * 16384 + row * 1024 + kb;
      double s = 0.0, q = 0.0;
#pragma unroll
      for (int j = 0; j < 64; ++j) { double v = hp[j]; a0[j] = v; s += v; q += v * v; }
#pragma unroll
      for (int mk = 1; mk <= 8; mk <<= 1) { s += __shfl_xor(s, mk); q += __shfl_xor(q, mk); }
      const double m0 = s * (1.0 / 1024.0);
      const double r0 = 1.0 / sqrt(q * (1.0 / 1024.0) - m0 * m0 + LN_EPS);
#pragma unroll
      for (int j = 0; j < 64; ++j)
        a0[j] = (a0[j] - m0) * r0 * (double)A.ln0w[kb + j] + (double)A.ln0b[kb + j];
#pragma unroll
      for (int cc = 0; cc < 4; ++cc) {
        const int c = col0 + cc;
#pragma unroll
        for (int g = 0; g < 3; ++g) {
          const float* wI = A.Wih1 + (size_t)(g * 1024 + c) * 1024 + kb;
          double aI = 0.0;
#pragma unroll
          for (int j = 0; j < 64; ++j) aI = fma(a0[j], (double)wI[j], aI);
#pragma unroll
          for (int mk = 1; mk <= 8; mk <<= 1) aI += __shfl_xor(aI, mk);
          gI[cc][g] = aI;
        }
      }
    }
    // ---- pass B: a1 = LN1(h1[t-1]), Whh1 dots, gates ----
    double a1[64];
    double m1 = 0.0, r1 = 0.0;
    if (t > 0) {
      const double* hp = A.h1ring + ((t - 1) & 1) * 16384 + row * 1024 + kb;
      double s = 0.0, q = 0.0;
#pragma unroll
      for (int j = 0; j < 64; ++j) { double v = hp[j]; a1[j] = v; s += v; q += v * v; }
#pragma unroll
      for (int mk = 1; mk <= 8; mk <<= 1) { s += __shfl_xor(s, mk); q += __shfl_xor(q, mk); }
      m1 = s * (1.0 / 1024.0);
      r1 = 1.0 / sqrt(q * (1.0 / 1024.0) - m1 * m1 + LN_EPS);
#pragma unroll
      for (int j = 0; j < 64; ++j)
        a1[j] = (a1[j] - m1) * r1 * (double)A.ln1w[kb + j] + (double)A.ln1b[kb + j];
    } else {
#pragma unroll
      for (int j = 0; j < 64; ++j) a1[j] = 0.0;
    }
#pragma unroll
    for (int cc = 0; cc < 4; ++cc) {
      const int c = col0 + cc;
      double gH[3];
#pragma unroll
      for (int g = 0; g < 3; ++g) {
        const float* wH = A.Whh1 + (size_t)(g * 1024 + c) * 1024 + kb;
        double aH = 0.0;
#pragma unroll
        for (int j = 0; j < 64; ++j) aH = fma(a1[j], (double)wH[j], aH);
#pragma unroll
        for (int mk = 1; mk <= 8; mk <<= 1) aH += __shfl_xor(aH, mk);
        gH[g] = aH;
      }
      const double ir = gI[cc][0] + (double)A.bih1[c],         hr = gH[0] + (double)A.bhh1[c];
      const double iz = gI[cc][1] + (double)A.bih1[c + 1024],  hz = gH[1] + (double)A.bhh1[c + 1024];
      const double in_ = gI[cc][2] + (double)A.bih1[c + 2048], hn = gH[2] + (double)A.bhh1[c + 2048];
      const double r_ = 1.0 / (1.0 + exp(-(ir + hr)));
      const double z = 1.0 / (1.0 + exp(-(iz + hz)));
      const double n = tanh(in_ + r_ * hn);
      double hprev = 0.0;
      if (t > 0) {
        const double praw = A.h1ring[((t - 1) & 1) * 16384 + row * 1024 + c];
        hprev = (praw - m1) * r1 * (double)A.ln1w[c] + (double)A.ln1b[c];
      }
      const double hnew = (1.0 - z) * n + z * hprev;
      if (ks == 0) A.h1ring[(t & 1) * 16384 + row * 1024 + c] = hnew;
    }
  } else {
    // ---------------- head pre-proj, t = p-2 ----------------
    const int t = A.p - 2;
    if (t < 0 || t >= TT) return;
    const int col0 = (bid - 384) * 16;  // 0..1008
    double a1n[64];
    {
      const double* hp = A.h1ring + (t & 1) * 16384 + row * 1024 + kb;
      double s = 0.0, q = 0.0;
#pragma unroll
      for (int j = 0; j < 64; ++j) { double v = hp[j]; a1n[j] = v; s += v; q += v * v; }
#pragma unroll
      for (int mk = 1; mk <= 8; mk <<= 1) { s += __shfl_xor(s, mk); q += __shfl_xor(q, mk); }
      const double m = s * (1.0 / 1024.0);
      const double r = 1.0 / sqrt(q * (1.0 / 1024.0) - m * m + LN_EPS);
#pragma unroll
      for (int j = 0; j < 64; ++j)
        a1n[j] = (a1n[j] - m) * r * (double)A.ln1w[kb + j] + (double)A.ln1b[kb + j];
    }
    for (int cc = 0; cc < 16; ++cc) {
      const int c = col0 + cc;
      const float* wp = A.W1 + (size_t)c * 1024 + kb;
      double acc = 0.0;
#pragma unroll
      for (int j = 0; j < 64; ++j) acc = fma(a1n[j], (double)wp[j], acc);
#pragma unroll
      for (int mk = 1; mk <= 8; mk <<= 1) acc += __shfl_xor(acc, mk);
      const double y = acc + (double)A.b1[c];
      const double a = y > 0.0 ? y : 0.01 * y;
      if (ks == 0) A.araw[((size_t)t * 16 + row) * 1024 + c] = f2bf((float)a);
    }
  }
}

// ---------------- head GEMM: LN2(araw) @ W2^T + b2, 128x128 tile bf16 MFMA ----------------
// (byte-identical to round 5 -- certified by the correlated round-5 result;
//  errors here do NOT amplify through the recurrence)
__global__ void k_head(const short* __restrict__ araw, const float* __restrict__ W2,
                       const float* __restrict__ ln2w, const float* __restrict__ ln2b,
                       const float* __restrict__ b2, float* __restrict__ C) {
  __shared__ __align__(16) short As[128 * 64];
  __shared__ __align__(16) short Bs[128 * 64];
  __shared__ float rowm[128], rowr[128];
  __shared__ float lnw_s[1024], lnb_s[1024];
  __shared__ float ps[256], pq[256];
  const int tid = threadIdx.x;
  const long brow = (long)blockIdx.y * 128;
  const long bcol = (long)blockIdx.x * 128;

  for (int i = tid; i < 1024; i += 256) { lnw_s[i] = ln2w[i]; lnb_s[i] = ln2b[i]; }
  {
    const int r2 = tid >> 1, hf = tid & 1;
    const short* ap = araw + (brow + r2) * 1024 + hf * 512;
    float s = 0.f, q = 0.f;
    for (int j = 0; j < 512; j += 8) {
      const bf16x8 v = *(const bf16x8*)(ap + j);
#pragma unroll
      for (int e = 0; e < 8; ++e) { const float x = bf2f(v[e]); s += x; q += x * x; }
    }
    ps[tid] = s; pq[tid] = q;
  }
  __syncthreads();
  if (tid < 128) {
    const float s = ps[2 * tid] + ps[2 * tid + 1];
    const float q = pq[2 * tid] + pq[2 * tid + 1];
    const float m = s * (1.f / 1024.f);
    rowm[tid] = m;
    rowr[tid] = rsqrtf(q * (1.f / 1024.f) - m * m + 1e-5f);
  }
  __syncthreads();

  const int l = tid & 63;
  const int w = tid >> 6;
  const int wm = w >> 1, wn = w & 1;
  const int lane15 = l & 15, lgrp = l >> 4;
  f32x4 zero4 = {0.f, 0.f, 0.f, 0.f};
  f32x4 acc[4][4];
#pragma unroll
  for (int ri = 0; ri < 4; ++ri)
#pragma unroll
    for (int ci = 0; ci < 4; ++ci) acc[ri][ci] = zero4;

  for (int k0 = 0; k0 < 1024; k0 += 64) {
    __syncthreads();
#pragma unroll
    for (int i = 0; i < 4; ++i) {
      const int c = tid + i * 256;
      const int r = c >> 3, cc = c & 7;
      const int k = k0 + cc * 8;
      {
        const bf16x8 v = *(const bf16x8*)(araw + (brow + r) * 1024 + k);
        const float mm = rowm[r], rr = rowr[r];
        bf16x8 o;
#pragma unroll
        for (int e = 0; e < 8; ++e)
          o[e] = f2bf((bf2f(v[e]) - mm) * rr * lnw_s[k + e] + lnb_s[k + e]);
        *(bf16x8*)&As[r * 64 + cc * 8] = o;
      }
      {
        const float4* bp = (const float4*)(W2 + (bcol + r) * 1024 + k);
        const float4 v0 = bp[0], v1 = bp[1];
        bf16x8 o;
        o[0] = f2bf(v0.x); o[1] = f2bf(v0.y); o[2] = f2bf(v0.z); o[3] = f2bf(v0.w);
        o[4] = f2bf(v1.x); o[5] = f2bf(v1.y); o[6] = f2bf(v1.z); o[7] = f2bf(v1.w);
        *(bf16x8*)&Bs[r * 64 + cc * 8] = o;
      }
    }
    __syncthreads();
#pragma unroll
    for (int kk = 0; kk < 2; ++kk) {
      const int ko = kk * 32 + lgrp * 8;
      bf16x8 av[4], bv[4];
#pragma unroll
      for (int ri = 0; ri < 4; ++ri) av[ri] = *(const bf16x8*)&As[(wm * 64 + ri * 16 + lane15) * 64 + ko];
#pragma unroll
      for (int ci = 0; ci < 4; ++ci) bv[ci] = *(const bf16x8*)&Bs[(wn * 64 + ci * 16 + lane15) * 64 + ko];
#pragma unroll
      for (int ri = 0; ri < 4; ++ri)
#pragma unroll
        for (int ci = 0; ci < 4; ++ci) acc[ri][ci] = mfma16(av[ri], bv[ci], acc[ri][ci]);
    }
  }
#pragma unroll
  for (int ri = 0; ri < 4; ++ri)
#pragma unroll
    for (int ci = 0; ci < 4; ++ci)
#pragma unroll
      for (int i = 0; i < 4; ++i) {
        const long mrow = brow + wm * 64 + ri * 16 + lgrp * 4 + i;
        const long ncol = bcol + wn * 64 + ci * 16 + lane15;
        const int tq = (int)(mrow >> 4), b = (int)(mrow & 15);
        C[(size_t)b * TT * VOCAB + (size_t)tq * VOCAB + ncol] = acc[ri][ci][i] + b2[ncol];
      }
}

// ---------------- host launch ----------------
extern "C" void kernel_launch(void* const* d_in, const int* in_sizes, int n_in,
                              void* d_out, int out_size, void* d_ws, size_t ws_size,
                              hipStream_t stream) {
  PH A;
  A.input = (const int*)d_in[0];
  A.embd = (const float*)d_in[1];
  A.Wih0 = (const float*)d_in[2];
  A.Whh0 = (const float*)d_in[3];
  A.bih0 = (const float*)d_in[4];
  A.bhh0 = (const float*)d_in[5];
  A.ln0w = (const float*)d_in[6];
  A.ln0b = (const float*)d_in[7];
  A.Wih1 = (const float*)d_in[8];
  A.Whh1 = (const float*)d_in[9];
  A.bih1 = (const float*)d_in[10];
  A.bhh1 = (const float*)d_in[11];
  A.ln1w = (const float*)d_in[12];
  A.ln1b = (const float*)d_in[13];
  A.W1 = (const float*)d_in[14];
  A.b1 = (const float*)d_in[15];
  const float* ln2w = (const float*)d_in[16];
  const float* ln2b = (const float*)d_in[17];
  const float* W2 = (const float*)d_in[18];
  const float* b2 = (const float*)d_in[19];
  float* out = (float*)d_out;

  // workspace: 8.6 MB total; d_out untouched until k_head writes all of it.
  char* ws = (char*)d_ws;
  size_t off = 0;
  auto alloc = [&](size_t bytes) -> char* {
    char* p = ws + off;
    off = (off + bytes + 255) & ~(size_t)255;
    return p;
  };
  A.h0ring = (double*)alloc(2ull * 16 * 1024 * 8);  // 256 KB
  A.h1ring = (double*)alloc(2ull * 16 * 1024 * 8);  // 256 KB
  A.araw = (short*)alloc(4096ull * 1024 * 2);       // 8 MB

  for (int p = 0; p < TT + 2; ++p) {
    A.p = p;
    k_phase<<<448, 256, 0, stream>>>(A);
  }

  k_head<<<dim3(250, 32), 256, 0, stream>>>(A.araw, W2, ln2w, ln2b, b2, out);
}

// Round 7
// 15923.306 us; speedup vs baseline: 2.0605x; 2.0605x over previous
//
#include <hip/hip_runtime.h>
#include <stdint.h>
#include <math.h>

#define TT 256
#define VOCAB 32000
#define LN_EPS 1e-5

typedef __attribute__((ext_vector_type(8))) short bf16x8;
typedef __attribute__((ext_vector_type(4))) float f32x4;

__device__ __forceinline__ float bf2f(short s) {
  return __uint_as_float(((uint32_t)(uint16_t)s) << 16);
}
__device__ __forceinline__ short f2bf(float f) {
  uint32_t u = __float_as_uint(f);
  u += 0x7fffu + ((u >> 16) & 1u);
  return (short)(u >> 16);
}
__device__ __forceinline__ f32x4 mfma16(bf16x8 a, bf16x8 b, f32x4 c) {
  return __builtin_amdgcn_mfma_f32_16x16x32_bf16(a, b, c, 0, 0, 0);
}

// ---------------- gi0 = embd[input] @ Wih0^T + bih0, f64, fully parallel ----------------
// grid 4096 = 256 t x 16 colgroups(192 cols); block 256 = 16 rows x 16 ct.
__global__ void k_gi0(const int* __restrict__ input, const float* __restrict__ embd,
                      const float* __restrict__ Wih0, const float* __restrict__ bih0,
                      double* __restrict__ gi0) {
  const int t = blockIdx.x >> 4;
  const int cg = blockIdx.x & 15;
  const int tid = threadIdx.x;
  __shared__ float xs[16][512];
  for (int idx = tid; idx < 16 * 512; idx += 256) {
    const int r = idx >> 9, j = idx & 511;
    const int tok = input[r * TT + t];
    xs[r][j] = embd[(size_t)tok * 512 + j];
  }
  __syncthreads();
  const int row = tid >> 4, ct = tid & 15;
  for (int i = 0; i < 12; ++i) {
    const int c = cg * 192 + ct + 16 * i;
    const float4* wp = (const float4*)(Wih0 + (size_t)c * 512);
    const float4* xp = (const float4*)&xs[row][0];
    double acc = 0.0;
#pragma unroll 8
    for (int j4 = 0; j4 < 128; ++j4) {
      const float4 w = wp[j4];
      const float4 x = xp[j4];
      acc = fma((double)x.x, (double)w.x, acc);
      acc = fma((double)x.y, (double)w.y, acc);
      acc = fma((double)x.z, (double)w.z, acc);
      acc = fma((double)x.w, (double)w.w, acc);
    }
    gi0[((size_t)t * 16 + row) * 3072 + c] = acc + (double)bih0[c];
  }
}

// ---------------- one pipeline phase per launch: L0(t=p) + L1(t=p-1) ----------------
// grid 192: blocks 0..63 layer0 (16 cols each), 64..191 layer1 (8 cols each).
// block 512 = 16 rows x 32 ks (32-element k-slices -> double a[32] = 64 VGPR, no spill).
// Dot sums -> LDS; gate stage is lane-parallel (1 thread per (row,col)).
struct SP {
  const float *Whh0, *bhh0, *ln0w, *ln0b;
  const float *Wih1, *Whh1, *bih1, *bhh1, *ln1w, *ln1b;
  const double* gi0;
  double *h0ring, *h1ring;  // [2][16][1024] f64 raw hidden states
  float* h1hist;            // [256*16][1024] f32 raw h1 history
  int p;
};

__launch_bounds__(512, 2)
__global__ void k_step(SP A) {
  __shared__ double sPre[16 * 16 * 3];  // L0: [row][16 cols][3]; L1: [row][8 cols][6]
  __shared__ double sM[16], sR[16];     // LN stats of own-layer h_prev (for z*hprev term)
  const int tid = threadIdx.x;
  const int row = tid >> 5;
  const int ks = tid & 31;
  const int bid = blockIdx.x;

  if (bid < 64) {
    // ================= layer0, t = p =================
    const int t = A.p;
    if (t >= TT) return;
    const int col0 = bid * 16;
    double a[32];
    if (t > 0) {
      const double* hp = A.h0ring + (size_t)((t - 1) & 1) * 16384 + row * 1024;
      double s = 0.0, q = 0.0;
#pragma unroll
      for (int g = 0; g < 8; ++g)
#pragma unroll
        for (int u = 0; u < 4; ++u) {
          const double v = hp[g * 128 + ks * 4 + u];
          a[g * 4 + u] = v; s += v; q += v * v;
        }
#pragma unroll
      for (int mk = 1; mk <= 16; mk <<= 1) { s += __shfl_xor(s, mk); q += __shfl_xor(q, mk); }
      const double m = s * (1.0 / 1024.0);
      const double rs = 1.0 / sqrt(q * (1.0 / 1024.0) - m * m + LN_EPS);
      if (ks == 0) { sM[row] = m; sR[row] = rs; }
#pragma unroll
      for (int g = 0; g < 8; ++g) {
        const float4 lw = *(const float4*)(A.ln0w + g * 128 + ks * 4);
        const float4 lb = *(const float4*)(A.ln0b + g * 128 + ks * 4);
        a[g * 4 + 0] = (a[g * 4 + 0] - m) * rs * (double)lw.x + (double)lb.x;
        a[g * 4 + 1] = (a[g * 4 + 1] - m) * rs * (double)lw.y + (double)lb.y;
        a[g * 4 + 2] = (a[g * 4 + 2] - m) * rs * (double)lw.z + (double)lb.z;
        a[g * 4 + 3] = (a[g * 4 + 3] - m) * rs * (double)lw.w + (double)lb.w;
      }
      for (int cc = 0; cc < 16; ++cc) {
        const int c = col0 + cc;
        const float4* pr = (const float4*)(A.Whh0 + (size_t)c * 1024);
        const float4* pz = (const float4*)(A.Whh0 + (size_t)(c + 1024) * 1024);
        const float4* pn = (const float4*)(A.Whh0 + (size_t)(c + 2048) * 1024);
        double ar = 0.0, az = 0.0, an_ = 0.0;
#pragma unroll
        for (int g = 0; g < 8; ++g) {
          const int o = g * 32 + ks;
          const float4 wr = pr[o], wz = pz[o], wn = pn[o];
          ar = fma(a[g*4+0], (double)wr.x, ar); ar = fma(a[g*4+1], (double)wr.y, ar);
          ar = fma(a[g*4+2], (double)wr.z, ar); ar = fma(a[g*4+3], (double)wr.w, ar);
          az = fma(a[g*4+0], (double)wz.x, az); az = fma(a[g*4+1], (double)wz.y, az);
          az = fma(a[g*4+2], (double)wz.z, az); az = fma(a[g*4+3], (double)wz.w, az);
          an_ = fma(a[g*4+0], (double)wn.x, an_); an_ = fma(a[g*4+1], (double)wn.y, an_);
          an_ = fma(a[g*4+2], (double)wn.z, an_); an_ = fma(a[g*4+3], (double)wn.w, an_);
        }
#pragma unroll
        for (int mk = 1; mk <= 16; mk <<= 1) {
          ar += __shfl_xor(ar, mk); az += __shfl_xor(az, mk); an_ += __shfl_xor(an_, mk);
        }
        if (ks == 0) {
          sPre[(row * 16 + cc) * 3 + 0] = ar;
          sPre[(row * 16 + cc) * 3 + 1] = az;
          sPre[(row * 16 + cc) * 3 + 2] = an_;
        }
      }
    } else {
      if (tid < 256) {
        sPre[tid * 3 + 0] = 0.0; sPre[tid * 3 + 1] = 0.0; sPre[tid * 3 + 2] = 0.0;
      }
    }
    __syncthreads();
    // gate stage: lane-parallel transcendentals, 1 thread per (row, col)
    if (tid < 256) {
      const int r2 = tid >> 4, cc = tid & 15;
      const int c = col0 + cc;
      const double ghr = sPre[(r2 * 16 + cc) * 3 + 0] + (double)A.bhh0[c];
      const double ghz = sPre[(r2 * 16 + cc) * 3 + 1] + (double)A.bhh0[c + 1024];
      const double ghn = sPre[(r2 * 16 + cc) * 3 + 2] + (double)A.bhh0[c + 2048];
      const double* gp = A.gi0 + ((size_t)t * 16 + r2) * 3072 + c;
      const double gir = gp[0], giz = gp[1024], gin = gp[2048];
      const double rg = 1.0 / (1.0 + exp(-(gir + ghr)));
      const double zg = 1.0 / (1.0 + exp(-(giz + ghz)));
      const double ng = tanh(gin + rg * ghn);
      double hprev = 0.0;
      if (t > 0) {
        const double praw = A.h0ring[(size_t)((t - 1) & 1) * 16384 + r2 * 1024 + c];
        hprev = (praw - sM[r2]) * sR[r2] * (double)A.ln0w[c] + (double)A.ln0b[c];
      }
      A.h0ring[(size_t)(t & 1) * 16384 + r2 * 1024 + c] = (1.0 - zg) * ng + zg * hprev;
    }
  } else {
    // ================= layer1, t = p-1 =================
    const int t = A.p - 1;
    if (t < 0 || t >= TT) return;
    const int col0 = (bid - 64) * 8;
    double a0[32], a1[32];
    // a0 = LN0(h0(t)) -- always available (written in phase p-1)
    {
      const double* hp = A.h0ring + (size_t)(t & 1) * 16384 + row * 1024;
      double s = 0.0, q = 0.0;
#pragma unroll
      for (int g = 0; g < 8; ++g)
#pragma unroll
        for (int u = 0; u < 4; ++u) {
          const double v = hp[g * 128 + ks * 4 + u];
          a0[g * 4 + u] = v; s += v; q += v * v;
        }
#pragma unroll
      for (int mk = 1; mk <= 16; mk <<= 1) { s += __shfl_xor(s, mk); q += __shfl_xor(q, mk); }
      const double m = s * (1.0 / 1024.0);
      const double rs = 1.0 / sqrt(q * (1.0 / 1024.0) - m * m + LN_EPS);
#pragma unroll
      for (int g = 0; g < 8; ++g) {
        const float4 lw = *(const float4*)(A.ln0w + g * 128 + ks * 4);
        const float4 lb = *(const float4*)(A.ln0b + g * 128 + ks * 4);
        a0[g * 4 + 0] = (a0[g * 4 + 0] - m) * rs * (double)lw.x + (double)lb.x;
        a0[g * 4 + 1] = (a0[g * 4 + 1] - m) * rs * (double)lw.y + (double)lb.y;
        a0[g * 4 + 2] = (a0[g * 4 + 2] - m) * rs * (double)lw.z + (double)lb.z;
        a0[g * 4 + 3] = (a0[g * 4 + 3] - m) * rs * (double)lw.w + (double)lb.w;
      }
    }
    // a1 = LN1(h1(t-1)) if t>0
    if (t > 0) {
      const double* hp = A.h1ring + (size_t)((t - 1) & 1) * 16384 + row * 1024;
      double s = 0.0, q = 0.0;
#pragma unroll
      for (int g = 0; g < 8; ++g)
#pragma unroll
        for (int u = 0; u < 4; ++u) {
          const double v = hp[g * 128 + ks * 4 + u];
          a1[g * 4 + u] = v; s += v; q += v * v;
        }
#pragma unroll
      for (int mk = 1; mk <= 16; mk <<= 1) { s += __shfl_xor(s, mk); q += __shfl_xor(q, mk); }
      const double m = s * (1.0 / 1024.0);
      const double rs = 1.0 / sqrt(q * (1.0 / 1024.0) - m * m + LN_EPS);
      if (ks == 0) { sM[row] = m; sR[row] = rs; }
#pragma unroll
      for (int g = 0; g < 8; ++g) {
        const float4 lw = *(const float4*)(A.ln1w + g * 128 + ks * 4);
        const float4 lb = *(const float4*)(A.ln1b + g * 128 + ks * 4);
        a1[g * 4 + 0] = (a1[g * 4 + 0] - m) * rs * (double)lw.x + (double)lb.x;
        a1[g * 4 + 1] = (a1[g * 4 + 1] - m) * rs * (double)lw.y + (double)lb.y;
        a1[g * 4 + 2] = (a1[g * 4 + 2] - m) * rs * (double)lw.z + (double)lb.z;
        a1[g * 4 + 3] = (a1[g * 4 + 3] - m) * rs * (double)lw.w + (double)lb.w;
      }
    } else {
#pragma unroll
      for (int j = 0; j < 32; ++j) a1[j] = 0.0;
    }
    for (int cc = 0; cc < 8; ++cc) {
      const int c = col0 + cc;
      const float4* ir = (const float4*)(A.Wih1 + (size_t)c * 1024);
      const float4* iz = (const float4*)(A.Wih1 + (size_t)(c + 1024) * 1024);
      const float4* in_ = (const float4*)(A.Wih1 + (size_t)(c + 2048) * 1024);
      const float4* hr = (const float4*)(A.Whh1 + (size_t)c * 1024);
      const float4* hz = (const float4*)(A.Whh1 + (size_t)(c + 1024) * 1024);
      const float4* hn = (const float4*)(A.Whh1 + (size_t)(c + 2048) * 1024);
      double sIr = 0.0, sIz = 0.0, sIn = 0.0, sHr = 0.0, sHz = 0.0, sHn = 0.0;
#pragma unroll
      for (int g = 0; g < 8; ++g) {
        const int o = g * 32 + ks;
        const float4 w0 = ir[o], w1 = iz[o], w2 = in_[o];
        const float4 w3 = hr[o], w4 = hz[o], w5 = hn[o];
        sIr = fma(a0[g*4+0], (double)w0.x, sIr); sIr = fma(a0[g*4+1], (double)w0.y, sIr);
        sIr = fma(a0[g*4+2], (double)w0.z, sIr); sIr = fma(a0[g*4+3], (double)w0.w, sIr);
        sIz = fma(a0[g*4+0], (double)w1.x, sIz); sIz = fma(a0[g*4+1], (double)w1.y, sIz);
        sIz = fma(a0[g*4+2], (double)w1.z, sIz); sIz = fma(a0[g*4+3], (double)w1.w, sIz);
        sIn = fma(a0[g*4+0], (double)w2.x, sIn); sIn = fma(a0[g*4+1], (double)w2.y, sIn);
        sIn = fma(a0[g*4+2], (double)w2.z, sIn); sIn = fma(a0[g*4+3], (double)w2.w, sIn);
        sHr = fma(a1[g*4+0], (double)w3.x, sHr); sHr = fma(a1[g*4+1], (double)w3.y, sHr);
        sHr = fma(a1[g*4+2], (double)w3.z, sHr); sHr = fma(a1[g*4+3], (double)w3.w, sHr);
        sHz = fma(a1[g*4+0], (double)w4.x, sHz); sHz = fma(a1[g*4+1], (double)w4.y, sHz);
        sHz = fma(a1[g*4+2], (double)w4.z, sHz); sHz = fma(a1[g*4+3], (double)w4.w, sHz);
        sHn = fma(a1[g*4+0], (double)w5.x, sHn); sHn = fma(a1[g*4+1], (double)w5.y, sHn);
        sHn = fma(a1[g*4+2], (double)w5.z, sHn); sHn = fma(a1[g*4+3], (double)w5.w, sHn);
      }
#pragma unroll
      for (int mk = 1; mk <= 16; mk <<= 1) {
        sIr += __shfl_xor(sIr, mk); sIz += __shfl_xor(sIz, mk); sIn += __shfl_xor(sIn, mk);
        sHr += __shfl_xor(sHr, mk); sHz += __shfl_xor(sHz, mk); sHn += __shfl_xor(sHn, mk);
      }
      if (ks == 0) {
        double* pp = &sPre[(row * 8 + cc) * 6];
        pp[0] = sIr; pp[1] = sIz; pp[2] = sIn; pp[3] = sHr; pp[4] = sHz; pp[5] = sHn;
      }
    }
    __syncthreads();
    if (tid < 128) {
      const int r2 = tid >> 3, cc = tid & 7;
      const int c = col0 + cc;
      const double* pp = &sPre[(r2 * 8 + cc) * 6];
      const double gir = pp[0] + (double)A.bih1[c];
      const double giz = pp[1] + (double)A.bih1[c + 1024];
      const double gin = pp[2] + (double)A.bih1[c + 2048];
      const double ghr = pp[3] + (double)A.bhh1[c];
      const double ghz = pp[4] + (double)A.bhh1[c + 1024];
      const double ghn = pp[5] + (double)A.bhh1[c + 2048];
      const double rg = 1.0 / (1.0 + exp(-(gir + ghr)));
      const double zg = 1.0 / (1.0 + exp(-(giz + ghz)));
      const double ng = tanh(gin + rg * ghn);
      double hprev = 0.0;
      if (t > 0) {
        const double praw = A.h1ring[(size_t)((t - 1) & 1) * 16384 + r2 * 1024 + c];
        hprev = (praw - sM[r2]) * sR[r2] * (double)A.ln1w[c] + (double)A.ln1b[c];
      }
      const double hnew = (1.0 - zg) * ng + zg * hprev;
      A.h1ring[(size_t)(t & 1) * 16384 + r2 * 1024 + c] = hnew;
      A.h1hist[((size_t)t * 16 + r2) * 1024 + c] = (float)hnew;
    }
  }
}

// ---------------- batched head pre-proj: araw = bf16(LeakyReLU(LN1(h1) @ W1^T + b1)) ----------------
// grid 256 (16 rows each); block 512 = 16 rows x 32 ks. f32 (non-amplifying path).
__launch_bounds__(512, 2)
__global__ void k_headpre(const float* __restrict__ h1hist, const float* __restrict__ ln1w,
                          const float* __restrict__ ln1b, const float* __restrict__ W1,
                          const float* __restrict__ b1, short* __restrict__ araw) {
  const int tid = threadIdx.x;
  const int row = tid >> 5, ks = tid & 31;
  const size_t m = (size_t)blockIdx.x * 16 + row;
  const float* hp = h1hist + m * 1024;
  float a[32];
  float s = 0.f, q = 0.f;
#pragma unroll
  for (int g = 0; g < 8; ++g) {
    const float4 v = *(const float4*)(hp + g * 128 + ks * 4);
    a[g*4+0] = v.x; a[g*4+1] = v.y; a[g*4+2] = v.z; a[g*4+3] = v.w;
    s += v.x + v.y + v.z + v.w;
    q += v.x * v.x + v.y * v.y + v.z * v.z + v.w * v.w;
  }
#pragma unroll
  for (int mk = 1; mk <= 16; mk <<= 1) { s += __shfl_xor(s, mk); q += __shfl_xor(q, mk); }
  const float mn = s * (1.f / 1024.f);
  const float rs = rsqrtf(q * (1.f / 1024.f) - mn * mn + 1e-5f);
#pragma unroll
  for (int g = 0; g < 8; ++g) {
    const float4 lw = *(const float4*)(ln1w + g * 128 + ks * 4);
    const float4 lb = *(const float4*)(ln1b + g * 128 + ks * 4);
    a[g*4+0] = (a[g*4+0] - mn) * rs * lw.x + lb.x;
    a[g*4+1] = (a[g*4+1] - mn) * rs * lw.y + lb.y;
    a[g*4+2] = (a[g*4+2] - mn) * rs * lw.z + lb.z;
    a[g*4+3] = (a[g*4+3] - mn) * rs * lw.w + lb.w;
  }
  for (int c = 0; c < 1024; ++c) {
    const float4* wp = (const float4*)(W1 + (size_t)c * 1024);
    float acc = 0.f;
#pragma unroll
    for (int g = 0; g < 8; ++g) {
      const float4 w = wp[g * 32 + ks];
      acc = fmaf(a[g*4+0], w.x, acc); acc = fmaf(a[g*4+1], w.y, acc);
      acc = fmaf(a[g*4+2], w.z, acc); acc = fmaf(a[g*4+3], w.w, acc);
    }
#pragma unroll
    for (int mk = 1; mk <= 16; mk <<= 1) acc += __shfl_xor(acc, mk);
    if (ks == 0) {
      const float y = acc + b1[c];
      araw[m * 1024 + c] = f2bf(y > 0.f ? y : 0.01f * y);
    }
  }
}

// ---------------- head GEMM: LN2(araw) @ W2^T + b2 (byte-identical to round 6) ----------------
__global__ void k_head(const short* __restrict__ araw, const float* __restrict__ W2,
                       const float* __restrict__ ln2w, const float* __restrict__ ln2b,
                       const float* __restrict__ b2, float* __restrict__ C) {
  __shared__ __align__(16) short As[128 * 64];
  __shared__ __align__(16) short Bs[128 * 64];
  __shared__ float rowm[128], rowr[128];
  __shared__ float lnw_s[1024], lnb_s[1024];
  __shared__ float ps[256], pq[256];
  const int tid = threadIdx.x;
  const long brow = (long)blockIdx.y * 128;
  const long bcol = (long)blockIdx.x * 128;

  for (int i = tid; i < 1024; i += 256) { lnw_s[i] = ln2w[i]; lnb_s[i] = ln2b[i]; }
  {
    const int r2 = tid >> 1, hf = tid & 1;
    const short* ap = araw + (brow + r2) * 1024 + hf * 512;
    float s = 0.f, q = 0.f;
    for (int j = 0; j < 512; j += 8) {
      const bf16x8 v = *(const bf16x8*)(ap + j);
#pragma unroll
      for (int e = 0; e < 8; ++e) { const float x = bf2f(v[e]); s += x; q += x * x; }
    }
    ps[tid] = s; pq[tid] = q;
  }
  __syncthreads();
  if (tid < 128) {
    const float s = ps[2 * tid] + ps[2 * tid + 1];
    const float q = pq[2 * tid] + pq[2 * tid + 1];
    const float m = s * (1.f / 1024.f);
    rowm[tid] = m;
    rowr[tid] = rsqrtf(q * (1.f / 1024.f) - m * m + 1e-5f);
  }
  __syncthreads();

  const int l = tid & 63;
  const int w = tid >> 6;
  const int wm = w >> 1, wn = w & 1;
  const int lane15 = l & 15, lgrp = l >> 4;
  f32x4 zero4 = {0.f, 0.f, 0.f, 0.f};
  f32x4 acc[4][4];
#pragma unroll
  for (int ri = 0; ri < 4; ++ri)
#pragma unroll
    for (int ci = 0; ci < 4; ++ci) acc[ri][ci] = zero4;

  for (int k0 = 0; k0 < 1024; k0 += 64) {
    __syncthreads();
#pragma unroll
    for (int i = 0; i < 4; ++i) {
      const int c = tid + i * 256;
      const int r = c >> 3, cc = c & 7;
      const int k = k0 + cc * 8;
      {
        const bf16x8 v = *(const bf16x8*)(araw + (brow + r) * 1024 + k);
        const float mm = rowm[r], rr = rowr[r];
        bf16x8 o;
#pragma unroll
        for (int e = 0; e < 8; ++e)
          o[e] = f2bf((bf2f(v[e]) - mm) * rr * lnw_s[k + e] + lnb_s[k + e]);
        *(bf16x8*)&As[r * 64 + cc * 8] = o;
      }
      {
        const float4* bp = (const float4*)(W2 + (bcol + r) * 1024 + k);
        const float4 v0 = bp[0], v1 = bp[1];
        bf16x8 o;
        o[0] = f2bf(v0.x); o[1] = f2bf(v0.y); o[2] = f2bf(v0.z); o[3] = f2bf(v0.w);
        o[4] = f2bf(v1.x); o[5] = f2bf(v1.y); o[6] = f2bf(v1.z); o[7] = f2bf(v1.w);
        *(bf16x8*)&Bs[r * 64 + cc * 8] = o;
      }
    }
    __syncthreads();
#pragma unroll
    for (int kk = 0; kk < 2; ++kk) {
      const int ko = kk * 32 + lgrp * 8;
      bf16x8 av[4], bv[4];
#pragma unroll
      for (int ri = 0; ri < 4; ++ri) av[ri] = *(const bf16x8*)&As[(wm * 64 + ri * 16 + lane15) * 64 + ko];
#pragma unroll
      for (int ci = 0; ci < 4; ++ci) bv[ci] = *(const bf16x8*)&Bs[(wn * 64 + ci * 16 + lane15) * 64 + ko];
#pragma unroll
      for (int ri = 0; ri < 4; ++ri)
#pragma unroll
        for (int ci = 0; ci < 4; ++ci) acc[ri][ci] = mfma16(av[ri], bv[ci], acc[ri][ci]);
    }
  }
#pragma unroll
  for (int ri = 0; ri < 4; ++ri)
#pragma unroll
    for (int ci = 0; ci < 4; ++ci)
#pragma unroll
      for (int i = 0; i < 4; ++i) {
        const long mrow = brow + wm * 64 + ri * 16 + lgrp * 4 + i;
        const long ncol = bcol + wn * 64 + ci * 16 + lane15;
        const int tq = (int)(mrow >> 4), b = (int)(mrow & 15);
        C[(size_t)b * TT * VOCAB + (size_t)tq * VOCAB + ncol] = acc[ri][ci][i] + b2[ncol];
      }
}

// ---------------- host launch ----------------
extern "C" void kernel_launch(void* const* d_in, const int* in_sizes, int n_in,
                              void* d_out, int out_size, void* d_ws, size_t ws_size,
                              hipStream_t stream) {
  const int* input = (const int*)d_in[0];
  const float* embd = (const float*)d_in[1];
  const float* Wih0 = (const float*)d_in[2];
  const float* Whh0 = (const float*)d_in[3];
  const float* bih0 = (const float*)d_in[4];
  const float* bhh0 = (const float*)d_in[5];
  const float* ln0w = (const float*)d_in[6];
  const float* ln0b = (const float*)d_in[7];
  const float* Wih1 = (const float*)d_in[8];
  const float* Whh1 = (const float*)d_in[9];
  const float* bih1 = (const float*)d_in[10];
  const float* bhh1 = (const float*)d_in[11];
  const float* ln1w = (const float*)d_in[12];
  const float* ln1b = (const float*)d_in[13];
  const float* W1 = (const float*)d_in[14];
  const float* b1 = (const float*)d_in[15];
  const float* ln2w = (const float*)d_in[16];
  const float* ln2b = (const float*)d_in[17];
  const float* W2 = (const float*)d_in[18];
  const float* b2 = (const float*)d_in[19];
  float* out = (float*)d_out;

  // ws (25.4 MB): rings + h1 history + araw.
  char* ws = (char*)d_ws;
  size_t off = 0;
  auto alloc = [&](size_t bytes) -> char* {
    char* p = ws + off;
    off = (off + bytes + 255) & ~(size_t)255;
    return p;
  };
  double* h0ring = (double*)alloc(2ull * 16 * 1024 * 8);
  double* h1ring = (double*)alloc(2ull * 16 * 1024 * 8);
  float* h1hist = (float*)alloc(4096ull * 1024 * 4);
  short* araw = (short*)alloc(4096ull * 1024 * 2);

  // gi0 (100.7 MB f64) lives in d_out-as-scratch: fully consumed by the last
  // k_step (p=255); k_head then overwrites every byte of d_out.
  double* gi0 = (double*)d_out;

  k_gi0<<<4096, 256, 0, stream>>>(input, embd, Wih0, bih0, gi0);

  SP A;
  A.Whh0 = Whh0; A.bhh0 = bhh0; A.ln0w = ln0w; A.ln0b = ln0b;
  A.Wih1 = Wih1; A.Whh1 = Whh1; A.bih1 = bih1; A.bhh1 = bhh1;
  A.ln1w = ln1w; A.ln1b = ln1b;
  A.gi0 = gi0; A.h0ring = h0ring; A.h1ring = h1ring; A.h1hist = h1hist;
  for (int p = 0; p <= TT; ++p) {
    A.p = p;
    k_step<<<192, 512, 0, stream>>>(A);
  }

  k_headpre<<<256, 512, 0, stream>>>(h1hist, ln1w, ln1b, W1, b1, araw);

  k_head<<<dim3(250, 32), 256, 0, stream>>>(araw, W2, ln2w, ln2b, b2, out);
}